// Round 1
// baseline (577.880 us; speedup 1.0000x reference)
//
#include <hip/hip_runtime.h>
#include <hip/hip_bf16.h>

// QuantizedLinear: out[M,N] = x[M,K] @ W[N,K]^T + bias, W = dequant(int4 packed, group-128 scales)
// M=8192 (4*2048), N=4096, K=4096. Strategy: fp32->bf16 convert x, dequant W to bf16,
// then m97-structure bf16 MFMA GEMM (128x128 tile, BK=32, global_load_lds width=16).

typedef __bf16 bf16x8 __attribute__((ext_vector_type(8)));
typedef float  f32x4  __attribute__((ext_vector_type(4)));

#define GAS __attribute__((address_space(1)))
#define LAS __attribute__((address_space(3)))

static constexpr int M_DIM = 8192;
static constexpr int N_DIM = 4096;
static constexpr int K_DIM = 4096;

// ---------------- x fp32 -> bf16 (8 elems/thread) ----------------
__global__ __launch_bounds__(256) void cvt_x(const float* __restrict__ x, __bf16* __restrict__ y) {
    long long i = ((long long)blockIdx.x * 256 + threadIdx.x) * 8;
    float4 a = *(const float4*)(x + i);
    float4 b = *(const float4*)(x + i + 4);
    bf16x8 v;
    v[0] = (__bf16)a.x; v[1] = (__bf16)a.y; v[2] = (__bf16)a.z; v[3] = (__bf16)a.w;
    v[4] = (__bf16)b.x; v[5] = (__bf16)b.y; v[6] = (__bf16)b.z; v[7] = (__bf16)b.w;
    *(bf16x8*)(y + i) = v;
}

// ---------------- int4-packed -> bf16 W[4096][4096] ----------------
// packed[o][j] (int32, value in [0,256)): low nibble -> k=2j, high -> k=2j+1, minus 8, * scales[o][k/128]
__global__ __launch_bounds__(256) void dequant_w(const int* __restrict__ wp,
                                                 const float* __restrict__ scales,
                                                 __bf16* __restrict__ wout) {
    int t  = blockIdx.x * 256 + threadIdx.x;     // 0 .. 4096*512-1
    int o  = t >> 9;                             // output row
    int j0 = (t & 511) << 2;                     // packed col, 4 per thread
    int4 p = *(const int4*)(wp + (long long)o * (K_DIM / 2) + j0);
    float s = scales[o * 32 + (j0 >> 6)];        // group = (2*j0)/128 = j0/64, constant across the 4-pack
    int pv[4] = {p.x, p.y, p.z, p.w};
    bf16x8 v;
#pragma unroll
    for (int i = 0; i < 4; ++i) {
        int b = pv[i];
        v[2 * i]     = (__bf16)(((b & 15) - 8) * s);
        v[2 * i + 1] = (__bf16)((((b >> 4) & 15) - 8) * s);
    }
    *(bf16x8*)(wout + (long long)o * K_DIM + 2 * j0) = v;
}

// ---------------- bf16 GEMM, B^T input (m97 structure) ----------------
// Block: 256 thr = 4 waves; tile 128x128, BK=32. Wave (wr,wc) owns 64x64 via 4x4 of 16x16x32 MFMA.
__global__ __launch_bounds__(256) void gemm_bt(const __bf16* __restrict__ A,
                                               const __bf16* __restrict__ B,
                                               const float* __restrict__ bias,
                                               float* __restrict__ C) {
    __shared__ __bf16 As[128 * 32];  // row-major [128][32], contiguous for global_load_lds
    __shared__ __bf16 Bs[128 * 32];

    const int tid  = threadIdx.x;
    const int l    = tid & 63;
    const int wv   = tid >> 6;        // wave 0..3
    const int wr   = wv >> 1;         // wave row 0..1
    const int wc   = wv & 1;          // wave col 0..1
    const int lr   = l & 15;          // row-in-16 (A frag) / col (B frag)
    const int quad = l >> 4;          // k-chunk 0..3

    const long long m0 = (long long)blockIdx.y * 128;
    const long long n0 = (long long)blockIdx.x * 128;

    const f32x4 vzero = {0.f, 0.f, 0.f, 0.f};
    f32x4 acc[4][4];
#pragma unroll
    for (int i = 0; i < 4; ++i)
#pragma unroll
        for (int j = 0; j < 4; ++j) acc[i][j] = vzero;

    for (int k0 = 0; k0 < K_DIM; k0 += 32) {
        __syncthreads();  // previous tile fully consumed
#pragma unroll
        for (int is = 0; is < 2; ++is) {
            // chunk c = wv*64 + is*256 + l ; row = c>>2 (32 bf16 = 4 chunks/row), cc = c&3
            int c   = wv * 64 + is * 256 + l;
            int row = c >> 2;
            int cc  = c & 3;
            const __bf16* ga = A + (m0 + row) * K_DIM + k0 + cc * 8;
            const __bf16* gb = B + (n0 + row) * K_DIM + k0 + cc * 8;
            // LDS dest: wave-uniform base + lane*16 (HW rule) => element offset (wv*64+is*256)*8
            __builtin_amdgcn_global_load_lds((const GAS void*)ga,
                                             (LAS void*)(As + (wv * 64 + is * 256) * 8), 16, 0, 0);
            __builtin_amdgcn_global_load_lds((const GAS void*)gb,
                                             (LAS void*)(Bs + (wv * 64 + is * 256) * 8), 16, 0, 0);
        }
        __syncthreads();  // compiler inserts vmcnt(0) drain here

        bf16x8 af[4], bfr[4];
#pragma unroll
        for (int i = 0; i < 4; ++i)
            af[i] = *(const bf16x8*)(As + (wr * 64 + i * 16 + lr) * 32 + quad * 8);
#pragma unroll
        for (int j = 0; j < 4; ++j)
            bfr[j] = *(const bf16x8*)(Bs + (wc * 64 + j * 16 + lr) * 32 + quad * 8);

#pragma unroll
        for (int i = 0; i < 4; ++i)
#pragma unroll
            for (int j = 0; j < 4; ++j)
                acc[i][j] = __builtin_amdgcn_mfma_f32_16x16x32_bf16(af[i], bfr[j], acc[i][j], 0, 0, 0);
    }

    // Epilogue: C/D layout col=lane&15, row=quad*4+reg
#pragma unroll
    for (int j = 0; j < 4; ++j) {
        int gn   = (int)n0 + wc * 64 + j * 16 + lr;
        float bv = bias[gn];
#pragma unroll
        for (int i = 0; i < 4; ++i) {
            long long gm = m0 + wr * 64 + i * 16 + quad * 4;
#pragma unroll
            for (int r = 0; r < 4; ++r)
                C[(gm + r) * N_DIM + gn] = acc[i][j][r] + bv;
        }
    }
}

extern "C" void kernel_launch(void* const* d_in, const int* in_sizes, int n_in,
                              void* d_out, int out_size, void* d_ws, size_t ws_size,
                              hipStream_t stream) {
    const float* x      = (const float*)d_in[0];   // [4,2048,4096] fp32
    const int*   wp     = (const int*)d_in[1];     // [4096,2048] int32 (byte semantics)
    const float* scales = (const float*)d_in[2];   // [4096,32]
    // d_in[3] = zeros (unused)
    const float* bias   = (const float*)d_in[4];   // [4096]
    float* out = (float*)d_out;                    // [4,2048,4096] fp32

    __bf16* Xb = (__bf16*)d_ws;                                            // 64 MB
    __bf16* Wb = (__bf16*)((char*)d_ws + (size_t)M_DIM * K_DIM * 2);       // +32 MB

    cvt_x<<<(M_DIM * K_DIM) / (256 * 8), 256, 0, stream>>>(x, Xb);
    dequant_w<<<(N_DIM * (K_DIM / 2) / 4) / 256, 256, 0, stream>>>(wp, scales, Wb);
    gemm_bt<<<dim3(N_DIM / 128, M_DIM / 128), 256, 0, stream>>>(Xb, Wb, bias, out);
}

// Round 2
// 540.671 us; speedup vs baseline: 1.0688x; 1.0688x over previous
//
#include <hip/hip_runtime.h>
#include <hip/hip_bf16.h>

// QuantizedLinear: out[M,N] = x[M,K] @ W[N,K]^T + bias, W = dequant(int4 packed, group-128 scales)
// M=8192, N=4096, K=4096. fp32->bf16 convert x; dequant W to bf16; bf16 MFMA GEMM.
// R2: BK=64 (32 MFMA per barrier, AITER-like density) + XOR bank swizzle (c ^ (row&7))
//     on the LDS layout. Swizzle is applied on the GATHER side of global_load_lds
//     (global chunk choice per lane), LDS side stays wave-uniform base + lane*16.

typedef __bf16 bf16x8 __attribute__((ext_vector_type(8)));
typedef float  f32x4  __attribute__((ext_vector_type(4)));

#define GAS __attribute__((address_space(1)))
#define LAS __attribute__((address_space(3)))

static constexpr int M_DIM = 8192;
static constexpr int N_DIM = 4096;
static constexpr int K_DIM = 4096;
static constexpr int BK    = 64;   // K-tile per barrier

// ---------------- x fp32 -> bf16 (8 elems/thread) ----------------
__global__ __launch_bounds__(256) void cvt_x(const float* __restrict__ x, __bf16* __restrict__ y) {
    long long i = ((long long)blockIdx.x * 256 + threadIdx.x) * 8;
    float4 a = *(const float4*)(x + i);
    float4 b = *(const float4*)(x + i + 4);
    bf16x8 v;
    v[0] = (__bf16)a.x; v[1] = (__bf16)a.y; v[2] = (__bf16)a.z; v[3] = (__bf16)a.w;
    v[4] = (__bf16)b.x; v[5] = (__bf16)b.y; v[6] = (__bf16)b.z; v[7] = (__bf16)b.w;
    *(bf16x8*)(y + i) = v;
}

// ---------------- int4-packed -> bf16 W[4096][4096] ----------------
__global__ __launch_bounds__(256) void dequant_w(const int* __restrict__ wp,
                                                 const float* __restrict__ scales,
                                                 __bf16* __restrict__ wout) {
    int t  = blockIdx.x * 256 + threadIdx.x;
    int o  = t >> 9;
    int j0 = (t & 511) << 2;
    int4 p = *(const int4*)(wp + (long long)o * (K_DIM / 2) + j0);
    float s = scales[o * 32 + (j0 >> 6)];
    int pv[4] = {p.x, p.y, p.z, p.w};
    bf16x8 v;
#pragma unroll
    for (int i = 0; i < 4; ++i) {
        int b = pv[i];
        v[2 * i]     = (__bf16)(((b & 15) - 8) * s);
        v[2 * i + 1] = (__bf16)((((b >> 4) & 15) - 8) * s);
    }
    *(bf16x8*)(wout + (long long)o * K_DIM + 2 * j0) = v;
}

// ---------------- bf16 GEMM, B^T input ----------------
// Block 256 thr = 4 waves; tile 128x128, BK=64. Wave (wr,wc) owns 64x64 via 4x4 of 16x16x32 MFMA.
// LDS layout: row r (of 128), 8 chunks of 8 bf16; chunk c stored at slot r*8 + (c ^ (r&7)).
__global__ __launch_bounds__(256) void gemm_bt(const __bf16* __restrict__ A,
                                               const __bf16* __restrict__ B,
                                               const float* __restrict__ bias,
                                               float* __restrict__ C) {
    __shared__ __bf16 As[128 * BK];   // 16 KB
    __shared__ __bf16 Bs[128 * BK];   // 16 KB

    const int tid  = threadIdx.x;
    const int l    = tid & 63;
    const int wv   = tid >> 6;        // wave 0..3
    const int wr   = wv >> 1;
    const int wc   = wv & 1;
    const int lr   = l & 15;
    const int quad = l >> 4;

    const long long m0 = (long long)blockIdx.y * 128;
    const long long n0 = (long long)blockIdx.x * 128;

    const f32x4 vzero = {0.f, 0.f, 0.f, 0.f};
    f32x4 acc[4][4];
#pragma unroll
    for (int i = 0; i < 4; ++i)
#pragma unroll
        for (int j = 0; j < 4; ++j) acc[i][j] = vzero;

    // Per-lane staging constants: this lane's slot within each 64-slot group
    // slot s = q*64 + l ; row = s>>3 ; stored-chunk = s&7 ; global chunk = (s&7) ^ (row&7)
    for (int k0 = 0; k0 < K_DIM; k0 += BK) {
        __syncthreads();  // previous tile fully consumed
#pragma unroll
        for (int q4 = 0; q4 < 4; ++q4) {
            int q   = wv * 4 + q4;            // 0..15, wave-uniform
            int s   = q * 64 + l;             // slot 0..1023
            int row = s >> 3;
            int c   = (s & 7) ^ (row & 7);    // global 16B-chunk index within the row
            const __bf16* ga = A + (m0 + row) * K_DIM + k0 + c * 8;
            const __bf16* gb = B + (n0 + row) * K_DIM + k0 + c * 8;
            __builtin_amdgcn_global_load_lds((const GAS void*)ga,
                                             (LAS void*)(As + q * 64 * 8), 16, 0, 0);
            __builtin_amdgcn_global_load_lds((const GAS void*)gb,
                                             (LAS void*)(Bs + q * 64 * 8), 16, 0, 0);
        }
        __syncthreads();  // vmcnt(0) drain + barrier

#pragma unroll
        for (int kk = 0; kk < 2; ++kk) {
            bf16x8 af[4], bfr[4];
#pragma unroll
            for (int i = 0; i < 4; ++i) {
                int row = wr * 64 + i * 16 + lr;
                int c   = kk * 4 + quad;
                af[i] = *(const bf16x8*)(As + (row * 8 + (c ^ (row & 7))) * 8);
            }
#pragma unroll
            for (int j = 0; j < 4; ++j) {
                int row = wc * 64 + j * 16 + lr;
                int c   = kk * 4 + quad;
                bfr[j] = *(const bf16x8*)(Bs + (row * 8 + (c ^ (row & 7))) * 8);
            }
#pragma unroll
            for (int i = 0; i < 4; ++i)
#pragma unroll
                for (int j = 0; j < 4; ++j)
                    acc[i][j] = __builtin_amdgcn_mfma_f32_16x16x32_bf16(af[i], bfr[j], acc[i][j], 0, 0, 0);
        }
    }

    // Epilogue: C/D layout col=lane&15, row=quad*4+reg
#pragma unroll
    for (int j = 0; j < 4; ++j) {
        int gn   = (int)n0 + wc * 64 + j * 16 + lr;
        float bv = bias[gn];
#pragma unroll
        for (int i = 0; i < 4; ++i) {
            long long gm = m0 + wr * 64 + i * 16 + quad * 4;
#pragma unroll
            for (int r = 0; r < 4; ++r)
                C[(gm + r) * N_DIM + gn] = acc[i][j][r] + bv;
        }
    }
}

extern "C" void kernel_launch(void* const* d_in, const int* in_sizes, int n_in,
                              void* d_out, int out_size, void* d_ws, size_t ws_size,
                              hipStream_t stream) {
    const float* x      = (const float*)d_in[0];   // [4,2048,4096] fp32
    const int*   wp     = (const int*)d_in[1];     // [4096,2048] int32 (byte semantics)
    const float* scales = (const float*)d_in[2];   // [4096,32]
    const float* bias   = (const float*)d_in[4];   // [4096]
    float* out = (float*)d_out;

    __bf16* Xb = (__bf16*)d_ws;                                            // 64 MB
    __bf16* Wb = (__bf16*)((char*)d_ws + (size_t)M_DIM * K_DIM * 2);       // +32 MB

    cvt_x<<<(M_DIM * K_DIM) / (256 * 8), 256, 0, stream>>>(x, Xb);
    dequant_w<<<(N_DIM * (K_DIM / 2) / 4) / 256, 256, 0, stream>>>(wp, scales, Wb);
    gemm_bt<<<dim3(N_DIM / 128, M_DIM / 128), 256, 0, stream>>>(Xb, Wb, bias, out);
}

// Round 3
// 442.101 us; speedup vs baseline: 1.3071x; 1.2230x over previous
//
#include <hip/hip_runtime.h>
#include <hip/hip_bf16.h>

// QuantizedLinear via int8 MFMA: out[M,N] = x[M,K] @ W[N,K]^T + bias
// W int4 is EXACT in i8 (unscaled); x quantized per-row to i8 (sx[m] = amax/127).
// GEMM: BK=128 = one scale group; i32 accumulate per group (exact), then
// accf += s[o,g] * (float)ci  drain; epilogue: out = accf*sx[m] + bias[o].
// LDS layout identical to the verified bf16 kernel (8x16B chunks/row, c^(row&7) swizzle).

typedef float f32x4 __attribute__((ext_vector_type(4)));
typedef int   i32x4 __attribute__((ext_vector_type(4)));

#define GAS __attribute__((address_space(1)))
#define LAS __attribute__((address_space(3)))

static constexpr int M_DIM = 8192;
static constexpr int N_DIM = 4096;
static constexpr int K_DIM = 4096;

// ---------------- x fp32 -> i8 per-row (one block per row of 4096) ----------------
__global__ __launch_bounds__(256) void quant_x(const float* __restrict__ x,
                                               signed char* __restrict__ xq,
                                               float* __restrict__ sx) {
    const int row = blockIdx.x;
    const int tid = threadIdx.x;
    const float* xr = x + (size_t)row * K_DIM;
    float4 v[4];
#pragma unroll
    for (int i = 0; i < 4; ++i) v[i] = *(const float4*)(xr + i * 1024 + tid * 4);
    float m = 0.f;
#pragma unroll
    for (int i = 0; i < 4; ++i)
        m = fmaxf(m, fmaxf(fmaxf(fabsf(v[i].x), fabsf(v[i].y)),
                           fmaxf(fabsf(v[i].z), fabsf(v[i].w))));
#pragma unroll
    for (int off = 32; off >= 1; off >>= 1) m = fmaxf(m, __shfl_xor(m, off, 64));
    __shared__ float wm[4];
    if ((tid & 63) == 0) wm[tid >> 6] = m;
    __syncthreads();
    m = fmaxf(fmaxf(wm[0], wm[1]), fmaxf(wm[2], wm[3]));
    const float inv = 127.f / m;
    if (tid == 0) sx[row] = m / 127.f;
#pragma unroll
    for (int i = 0; i < 4; ++i) {
        int b0 = (int)rintf(v[i].x * inv) & 255;
        int b1 = (int)rintf(v[i].y * inv) & 255;
        int b2 = (int)rintf(v[i].z * inv) & 255;
        int b3 = (int)rintf(v[i].w * inv) & 255;
        *(int*)(xq + (size_t)row * K_DIM + i * 1024 + tid * 4) =
            b0 | (b1 << 8) | (b2 << 16) | (b3 << 24);
    }
}

// ---------------- packed int4 -> raw i8 (values q-8 in [-8,7], NO scale) ----------------
__global__ __launch_bounds__(256) void unpack_w(const int* __restrict__ wp,
                                                signed char* __restrict__ wq) {
    const int t = blockIdx.x * 256 + threadIdx.x;   // 4 packed words -> 8 bytes out
    int4 p = *(const int4*)(wp + (size_t)t * 4);
    int pv[4] = {p.x, p.y, p.z, p.w};
    int w01 = (((pv[0] & 15) - 8) & 255) | (((((pv[0] >> 4) & 15) - 8) & 255) << 8) |
              ((((pv[1] & 15) - 8) & 255) << 16) | (((((pv[1] >> 4) & 15) - 8) & 255) << 24);
    int w23 = (((pv[2] & 15) - 8) & 255) | (((((pv[2] >> 4) & 15) - 8) & 255) << 8) |
              ((((pv[3] & 15) - 8) & 255) << 16) | (((((pv[3] >> 4) & 15) - 8) & 255) << 24);
    *(int2*)(wq + (size_t)t * 8) = make_int2(w01, w23);
}

// ---------------- i8 GEMM, B^T, BK=128 (= one scale group) ----------------
// Block 256 thr = 4 waves; tile 128x128. Wave (wr,wc) owns 64x64 via 4x4 of 16x16x64 i8 MFMA.
// LDS row = 128 B = 8 chunks of 16 B; chunk c stored at slot c ^ (row&7) (swizzle, 0 conflicts).
__global__ __launch_bounds__(256, 3) void gemm_i8(const signed char* __restrict__ A,
                                                  const signed char* __restrict__ B,
                                                  const float* __restrict__ scales,
                                                  const float* __restrict__ sx,
                                                  const float* __restrict__ bias,
                                                  float* __restrict__ C) {
    __shared__ signed char As[128 * 128];  // 16 KB
    __shared__ signed char Bs[128 * 128];  // 16 KB

    const int tid  = threadIdx.x;
    const int l    = tid & 63;
    const int wv   = tid >> 6;
    const int wr   = wv >> 1;
    const int wc   = wv & 1;
    const int lr   = l & 15;
    const int quad = l >> 4;

    const size_t m0 = (size_t)blockIdx.y * 128;
    const size_t n0 = (size_t)blockIdx.x * 128;

    float accf[4][4][4];
#pragma unroll
    for (int i = 0; i < 4; ++i)
#pragma unroll
        for (int j = 0; j < 4; ++j)
#pragma unroll
            for (int r = 0; r < 4; ++r) accf[i][j][r] = 0.f;

    const i32x4 izero = {0, 0, 0, 0};

    for (int g = 0; g < K_DIM / 128; ++g) {
        const int k0 = g * 128;
        __syncthreads();  // previous tile fully consumed
#pragma unroll
        for (int q4 = 0; q4 < 4; ++q4) {
            int q   = wv * 4 + q4;           // wave-uniform slot group
            int s   = q * 64 + l;
            int row = s >> 3;
            int c   = (s & 7) ^ (row & 7);   // gather-side swizzle
            const signed char* ga = A + (m0 + row) * K_DIM + k0 + c * 16;
            const signed char* gb = B + (n0 + row) * K_DIM + k0 + c * 16;
            __builtin_amdgcn_global_load_lds((const GAS void*)ga, (LAS void*)(As + q * 1024), 16, 0, 0);
            __builtin_amdgcn_global_load_lds((const GAS void*)gb, (LAS void*)(Bs + q * 1024), 16, 0, 0);
        }
        // group scales for this wave's 4 output-column tiles (L1/L2-hot after g=0)
        float sj[4];
#pragma unroll
        for (int j = 0; j < 4; ++j)
            sj[j] = scales[(n0 + (size_t)wc * 64 + j * 16 + lr) * 32 + g];
        __syncthreads();  // staging drained (vmcnt(0) + barrier)

        i32x4 bf0[4], bf1[4];
#pragma unroll
        for (int j = 0; j < 4; ++j) {
            int row = wc * 64 + j * 16 + lr;
            bf0[j] = *(const i32x4*)(Bs + (row * 8 + (quad ^ (row & 7))) * 16);
            bf1[j] = *(const i32x4*)(Bs + (row * 8 + ((4 + quad) ^ (row & 7))) * 16);
        }
#pragma unroll
        for (int i = 0; i < 4; ++i) {
            int row = wr * 64 + i * 16 + lr;
            i32x4 a0 = *(const i32x4*)(As + (row * 8 + (quad ^ (row & 7))) * 16);
            i32x4 a1 = *(const i32x4*)(As + (row * 8 + ((4 + quad) ^ (row & 7))) * 16);
            i32x4 ci[4];
#pragma unroll
            for (int j = 0; j < 4; ++j)
                ci[j] = __builtin_amdgcn_mfma_i32_16x16x64_i8(a0, bf0[j], izero, 0, 0, 0);
#pragma unroll
            for (int j = 0; j < 4; ++j)
                ci[j] = __builtin_amdgcn_mfma_i32_16x16x64_i8(a1, bf1[j], ci[j], 0, 0, 0);
#pragma unroll
            for (int j = 0; j < 4; ++j)
#pragma unroll
                for (int r = 0; r < 4; ++r)
                    accf[i][j][r] += sj[j] * (float)ci[j][r];
        }
    }

    // Epilogue: C/D layout col=lane&15, row=quad*4+reg (verified, dtype-independent)
    float sxr[4][4];
#pragma unroll
    for (int i = 0; i < 4; ++i)
#pragma unroll
        for (int r = 0; r < 4; ++r)
            sxr[i][r] = sx[m0 + wr * 64 + i * 16 + quad * 4 + r];
#pragma unroll
    for (int j = 0; j < 4; ++j) {
        int gn   = (int)n0 + wc * 64 + j * 16 + lr;
        float bv = bias[gn];
#pragma unroll
        for (int i = 0; i < 4; ++i) {
            size_t gm = m0 + wr * 64 + i * 16 + quad * 4;
#pragma unroll
            for (int r = 0; r < 4; ++r)
                C[(gm + r) * N_DIM + gn] = accf[i][j][r] * sxr[i][r] + bv;
        }
    }
}

extern "C" void kernel_launch(void* const* d_in, const int* in_sizes, int n_in,
                              void* d_out, int out_size, void* d_ws, size_t ws_size,
                              hipStream_t stream) {
    const float* x      = (const float*)d_in[0];   // [4,2048,4096] fp32
    const int*   wp     = (const int*)d_in[1];     // [4096,2048] int32 (uint8 semantics)
    const float* scales = (const float*)d_in[2];   // [4096,32]
    const float* bias   = (const float*)d_in[4];   // [4096]
    float* out = (float*)d_out;

    signed char* Xq = (signed char*)d_ws;                                   // 32 MB
    signed char* Wq = (signed char*)d_ws + (size_t)M_DIM * K_DIM;           // +16 MB
    float*       sx = (float*)((char*)d_ws + (size_t)M_DIM * K_DIM + (size_t)N_DIM * K_DIM);  // +32 KB

    quant_x<<<M_DIM, 256, 0, stream>>>(x, Xq, sx);
    unpack_w<<<(N_DIM * (K_DIM / 2) / 4) / 256, 256, 0, stream>>>(wp, Wq);
    gemm_i8<<<dim3(N_DIM / 128, M_DIM / 128), 256, 0, stream>>>(Xq, Wq, scales, sx, bias, out);
}